// Round 1
// baseline (174.386 us; speedup 1.0000x reference)
//
#include <hip/hip_runtime.h>

typedef _Float16 f16;
typedef _Float16 f16x8 __attribute__((ext_vector_type(8)));
typedef float    f32x4 __attribute__((ext_vector_type(4)));

constexpr int B_ = 2, H_ = 16, T_ = 2048, D_ = 64, R_ = 32;
constexpr int NT = T_ / 64;   // 32 row-tiles of 64

__device__ __forceinline__ f32x4 mfma16(f16x8 a, f16x8 b, f32x4 c) {
  return __builtin_amdgcn_mfma_f32_16x16x32_f16(a, b, c, 0, 0, 0);
}

// ---------------- Kernel A: low-rank projections + V transpose ----------------
// qlr[bh][t][r] = f16( (q[bh,t,:]@Wq[h][:,r]) * kron[h,r] / sqrt(32) )
// klr[bh][t][r] = f16( k[bh,t,:]@Wk[h][:,r] )
// vt [bh][d][t] = f16( v[bh,t,d] )
__global__ __launch_bounds__(256) void proj_kernel(
    const float* __restrict__ q, const float* __restrict__ k, const float* __restrict__ v,
    const float* __restrict__ Wq, const float* __restrict__ Wk,
    const float* __restrict__ c1, const float* __restrict__ c2,
    f16* __restrict__ qlr, f16* __restrict__ klr, f16* __restrict__ vt)
{
  __shared__ float sq[64 * 68];     // [t][d], stride 68 keeps float4 alignment
  __shared__ float sk[64 * 68];
  __shared__ float sv[64 * 65];     // scalar access only; stride 65 = conflict-free transpose
  __shared__ float sWqT[32 * 68];   // [r][d]
  __shared__ float sWkT[32 * 68];
  __shared__ float skron[32];

  const int tid = threadIdx.x;
  const int bh  = blockIdx.x / NT;
  const int h   = bh % H_;
  const int t0  = (blockIdx.x % NT) * 64;

  const float* qb = q + ((size_t)bh * T_ + t0) * D_;
  const float* kb = k + ((size_t)bh * T_ + t0) * D_;
  const float* vb = v + ((size_t)bh * T_ + t0) * D_;
#pragma unroll
  for (int it = 0; it < 16; ++it) {
    int idx = it * 256 + tid; int t = idx >> 6, d = idx & 63;
    sq[t * 68 + d] = qb[idx];
    sk[t * 68 + d] = kb[idx];
    sv[t * 65 + d] = vb[idx];
  }
#pragma unroll
  for (int it = 0; it < 8; ++it) {
    int idx = it * 256 + tid; int d = idx >> 5, rr = idx & 31;   // Wq row-major [d][r]
    sWqT[rr * 68 + d] = Wq[(size_t)h * D_ * R_ + idx];
    sWkT[rr * 68 + d] = Wk[(size_t)h * D_ * R_ + idx];
  }
  if (tid < 32)
    skron[tid] = c1[h * 4 + (tid >> 3)] * c2[h * 8 + (tid & 7)] * 0.1767766952966369f;
  __syncthreads();

  const int r  = tid & 31;   // this thread's rank column (fixed -> W row cached in regs)
  const int tg = tid >> 5;   // 0..7
  float4 wr[16];
#pragma unroll
  for (int c = 0; c < 16; ++c) wr[c] = *(const float4*)&sWqT[r * 68 + 4 * c];
  const float kr = skron[r];
#pragma unroll
  for (int it = 0; it < 8; ++it) {
    int t = it * 8 + tg;
    float acc = 0.f;
#pragma unroll
    for (int c = 0; c < 16; ++c) {
      float4 a = *(const float4*)&sq[t * 68 + 4 * c];
      acc += a.x * wr[c].x + a.y * wr[c].y + a.z * wr[c].z + a.w * wr[c].w;
    }
    qlr[((size_t)bh * T_ + t0 + t) * R_ + r] = (f16)(acc * kr);
  }
#pragma unroll
  for (int c = 0; c < 16; ++c) wr[c] = *(const float4*)&sWkT[r * 68 + 4 * c];
#pragma unroll
  for (int it = 0; it < 8; ++it) {
    int t = it * 8 + tg;
    float acc = 0.f;
#pragma unroll
    for (int c = 0; c < 16; ++c) {
      float4 a = *(const float4*)&sk[t * 68 + 4 * c];
      acc += a.x * wr[c].x + a.y * wr[c].y + a.z * wr[c].z + a.w * wr[c].w;
    }
    klr[((size_t)bh * T_ + t0 + t) * R_ + r] = (f16)acc;
  }
  // V transpose: vt[bh][d][t0+t] = v[bh][t0+t][d]
#pragma unroll
  for (int it = 0; it < 16; ++it) {
    int idx = it * 256 + tid; int d = idx >> 6, t = idx & 63;
    vt[((size_t)bh * D_ + d) * T_ + t0 + t] = (f16)sv[t * 65 + d];
  }
}

// ---------------- Kernel B: flash attention over rank-32 scores ----------------
// Block: 64 q-rows of one (b,h). 4 waves; wave w owns rows [16w,16w+16).
// Per 64-col k-tile: S = Qlr@Klr^T (1 MFMA/16-col tile, K=32), online softmax
// in C/D layout, P via LDS (C-layout -> A-layout), O += P@V (8 MFMAs/wave).
__global__ __launch_bounds__(256) void attn_kernel(
    const f16* __restrict__ qlr, const f16* __restrict__ klr,
    const f16* __restrict__ vt, float* __restrict__ out)
{
  __shared__ __align__(16) f16 s_k[64 * 32];      // [n][r]
  __shared__ __align__(16) f16 s_vt[64 * 72];     // [d][n], stride 72 (144B rows, 16B aligned)
  __shared__ __align__(16) f16 s_p[4][16 * 72];   // per-wave P, [row_loc][n]

  const int tid  = threadIdx.x;
  const int w    = tid >> 6;
  const int lane = tid & 63;
  const int l15  = lane & 15;
  const int l4   = lane >> 4;

  const int bh = blockIdx.x & 31;
  const int mt = 31 - (blockIdx.x >> 5);   // longest rows dispatch first
  const int m0 = mt * 64;

  // persistent Q A-frag: A[m=lane&15][k=(lane>>4)*8+j]
  const f16x8 aq = *(const f16x8*)(qlr + ((size_t)bh * T_ + m0 + 16 * w + l15) * R_ + 8 * l4);

  const f32x4 f4z = {0.f, 0.f, 0.f, 0.f};
  f32x4 oacc[4];                 // d-tiles 0..3; C/D layout rows 4*l4+i, col l15
  float mi[4], li[4];
#pragma unroll
  for (int i = 0; i < 4; ++i) { oacc[i] = f4z; mi[i] = -1e30f; li[i] = 0.f; }

  for (int kt = 0; kt <= mt; ++kt) {
    const int n0 = kt * 64;
    __syncthreads();   // prev PV done before restaging s_k/s_vt
    {
      int n = tid >> 2, c = tid & 3;   // 64 rows x 64B
      ((uint4*)&s_k[n * 32])[c] = ((const uint4*)(klr + ((size_t)bh * T_ + n0 + n) * R_))[c];
    }
#pragma unroll
    for (int it = 0; it < 2; ++it) {   // 64 d-rows x 128B
      int idx = it * 256 + tid; int d = idx >> 3, c = idx & 7;
      ((uint4*)&s_vt[d * 72])[c] = ((const uint4*)(vt + ((size_t)bh * D_ + d) * T_ + n0))[c];
    }
    __syncthreads();

    // ---- S = Qlr @ Klr^T ----
    f32x4 sc[4];
#pragma unroll
    for (int c = 0; c < 4; ++c) {
      f16x8 bk = *(const f16x8*)&s_k[(16 * c + l15) * 32 + 8 * l4];
      sc[c] = mfma16(aq, bk, f4z);
    }
    // causal mask, diagonal tile only (m0 == n0 there)
    if (kt == mt) {
#pragma unroll
      for (int c = 0; c < 4; ++c) {
        int nloc = 16 * c + l15;
#pragma unroll
        for (int i = 0; i < 4; ++i)
          if (nloc > 16 * w + 4 * l4 + i) sc[c][i] = -1e30f;
      }
    }
    // ---- online softmax (rows live across 16 lanes of a quad) ----
    float mnew[4], alpha[4], rs[4];
#pragma unroll
    for (int i = 0; i < 4; ++i) {
      float rm = fmaxf(fmaxf(sc[0][i], sc[1][i]), fmaxf(sc[2][i], sc[3][i]));
      rm = fmaxf(rm, __shfl_xor(rm, 1, 16));
      rm = fmaxf(rm, __shfl_xor(rm, 2, 16));
      rm = fmaxf(rm, __shfl_xor(rm, 4, 16));
      rm = fmaxf(rm, __shfl_xor(rm, 8, 16));
      mnew[i]  = fmaxf(mi[i], rm);
      alpha[i] = __expf(mi[i] - mnew[i]);   // mi=-1e30 first pass -> 0 (or 1 if row untouched)
      rs[i]    = 0.f;
    }
#pragma unroll
    for (int c = 0; c < 4; ++c)
#pragma unroll
      for (int i = 0; i < 4; ++i) {
        float p = __expf(sc[c][i] - mnew[i]);   // masked -> exp(-huge) = 0
        rs[i] += p;
        s_p[w][(4 * l4 + i) * 72 + 16 * c + l15] = (f16)p;
      }
#pragma unroll
    for (int i = 0; i < 4; ++i) {
      rs[i] += __shfl_xor(rs[i], 1, 16);
      rs[i] += __shfl_xor(rs[i], 2, 16);
      rs[i] += __shfl_xor(rs[i], 4, 16);
      rs[i] += __shfl_xor(rs[i], 8, 16);
      li[i] = li[i] * alpha[i] + rs[i];
      mi[i] = mnew[i];
#pragma unroll
      for (int c = 0; c < 4; ++c) oacc[c][i] *= alpha[i];
    }
    __syncthreads();   // s_p visible (conservative; s_p is wave-private)

    // ---- O += P @ V ----
#pragma unroll
    for (int h2 = 0; h2 < 2; ++h2) {
      f16x8 ap = *(const f16x8*)&s_p[w][l15 * 72 + 32 * h2 + 8 * l4];   // A[m=l15][k=n]
#pragma unroll
      for (int c = 0; c < 4; ++c) {
        f16x8 bv = *(const f16x8*)&s_vt[(16 * c + l15) * 72 + 32 * h2 + 8 * l4]; // B[k=n][d=l15]
        oacc[c] = mfma16(ap, bv, oacc[c]);
      }
    }
  }

  // ---- epilogue: normalize + store ----
#pragma unroll
  for (int i = 0; i < 4; ++i) {
    float inv = 1.f / li[i];
    size_t row = ((size_t)bh * T_ + m0 + 16 * w + 4 * l4 + i) * D_;
#pragma unroll
    for (int c = 0; c < 4; ++c)
      out[row + 16 * c + l15] = oacc[c][i] * inv;
  }
}

extern "C" void kernel_launch(void* const* d_in, const int* in_sizes, int n_in,
                              void* d_out, int out_size, void* d_ws, size_t ws_size,
                              hipStream_t stream) {
  const float* q  = (const float*)d_in[0];
  const float* k  = (const float*)d_in[1];
  const float* v  = (const float*)d_in[2];
  const float* Wq = (const float*)d_in[3];
  const float* Wk = (const float*)d_in[4];
  const float* c1 = (const float*)d_in[5];
  const float* c2 = (const float*)d_in[6];
  float* out = (float*)d_out;

  f16* qlr = (f16*)d_ws;                              // 2*16*2048*32 = 2,097,152 elems
  f16* klr = qlr + (size_t)B_ * H_ * T_ * R_;         // + 4 MiB
  f16* vt  = klr + (size_t)B_ * H_ * T_ * R_;         // + 4 MiB (vt itself 8 MiB)

  proj_kernel<<<B_ * H_ * NT, 256, 0, stream>>>(q, k, v, Wq, Wk, c1, c2, qlr, klr, vt);
  attn_kernel<<<B_ * H_ * NT, 256, 0, stream>>>(qlr, klr, vt, out);
}

// Round 2
// 162.010 us; speedup vs baseline: 1.0764x; 1.0764x over previous
//
#include <hip/hip_runtime.h>

typedef _Float16 f16;
typedef _Float16 f16x2 __attribute__((ext_vector_type(2)));
typedef _Float16 f16x4 __attribute__((ext_vector_type(4)));
typedef _Float16 f16x8 __attribute__((ext_vector_type(8)));
typedef float    f32x4 __attribute__((ext_vector_type(4)));
typedef float    f32x16 __attribute__((ext_vector_type(16)));

constexpr int B_ = 2, H_ = 16, T_ = 2048, D_ = 64, R_ = 32, NT = 32;

__device__ __forceinline__ f32x4 mfma16(f16x8 a, f16x8 b, f32x4 c) {
  return __builtin_amdgcn_mfma_f32_16x16x32_f16(a, b, c, 0, 0, 0);
}
__device__ __forceinline__ f32x16 mfma32(f16x8 a, f16x8 b, f32x16 c) {
  return __builtin_amdgcn_mfma_f32_32x32x16_f16(a, b, c, 0, 0, 0);
}
// async global->LDS DMA, 16B/lane. LDS dest = wave-uniform base + lane*16.
__device__ __forceinline__ void ld_lds16(const void* g, void* l) {
  __builtin_amdgcn_global_load_lds(
      (const __attribute__((address_space(1))) unsigned int*)g,
      (__attribute__((address_space(3))) unsigned int*)l, 16, 0, 0);
}

// ---------------- Kernel A: MFMA projections + swizzled V^T ----------------
// qlr[bh][t][r] = f16( (q@Wq)[t][r] * kron[h,r] * log2e/sqrt(32) )
// klr[bh][t][r] = f16( (k@Wk)[t][r] )
// vt [bh][d][t] = f16( v[t][d] ), 16B units XOR-swizzled within 64-t chunks:
//   unit u = (t&63)>>3 stored at u^(d&7)  (makes un-padded LDS tiles conflict-free)
__global__ __launch_bounds__(256) void proj_kernel(
    const float* __restrict__ q, const float* __restrict__ k, const float* __restrict__ v,
    const float* __restrict__ Wq, const float* __restrict__ Wk,
    const float* __restrict__ c1, const float* __restrict__ c2,
    f16* __restrict__ qlr, f16* __restrict__ klr, f16* __restrict__ vt)
{
  __shared__ float sv[64 * 65];   // [t][d], stride 65: scalar access, conflict-free transpose

  const int tid = threadIdx.x, w = tid >> 6, lane = tid & 63;
  const int l15 = lane & 15, l4 = lane >> 4;
  const int bh = blockIdx.x >> 5, h = bh & (H_ - 1);
  const int t0 = (blockIdx.x & 31) * 64;

  // ---- global loads first (latency overlap) ----
  const float* vb = v + ((size_t)bh * T_ + t0) * D_;
  float4 vld[4];
#pragma unroll
  for (int it = 0; it < 4; ++it) vld[it] = ((const float4*)vb)[it * 256 + tid];

  // A-frags of q,k: A[m=l15][k=8*l4+j], rows m = t0+16w+l15
  const int m = t0 + 16 * w + l15;
  const float* qr = q + ((size_t)bh * T_ + m) * D_;
  const float* kr = k + ((size_t)bh * T_ + m) * D_;
  f16x8 aq[2], ak[2];
#pragma unroll
  for (int kc = 0; kc < 2; ++kc) {
    float4 x0 = *(const float4*)(qr + kc * 32 + 8 * l4);
    float4 x1 = *(const float4*)(qr + kc * 32 + 8 * l4 + 4);
    float4 y0 = *(const float4*)(kr + kc * 32 + 8 * l4);
    float4 y1 = *(const float4*)(kr + kc * 32 + 8 * l4 + 4);
    f16x8 A, K;
    A[0]=(f16)x0.x; A[1]=(f16)x0.y; A[2]=(f16)x0.z; A[3]=(f16)x0.w;
    A[4]=(f16)x1.x; A[5]=(f16)x1.y; A[6]=(f16)x1.z; A[7]=(f16)x1.w;
    K[0]=(f16)y0.x; K[1]=(f16)y0.y; K[2]=(f16)y0.z; K[3]=(f16)y0.w;
    K[4]=(f16)y1.x; K[5]=(f16)y1.y; K[6]=(f16)y1.z; K[7]=(f16)y1.w;
    aq[kc] = A; ak[kc] = K;
  }

  // B-frags of W: B[k=d][col=r], d = kc*32+8*l4+j, r = 16*nt+l15 (L2-hot scalar loads)
  const float* Wqh = Wq + (size_t)h * D_ * R_;
  const float* Wkh = Wk + (size_t)h * D_ * R_;
  f16x8 bq[2][2], bk[2][2];
#pragma unroll
  for (int kc = 0; kc < 2; ++kc)
#pragma unroll
    for (int nt = 0; nt < 2; ++nt) {
      const int r = 16 * nt + l15;
      f16x8 q8, k8;
#pragma unroll
      for (int j2 = 0; j2 < 8; ++j2) {
        const int d = kc * 32 + 8 * l4 + j2;
        q8[j2] = (f16)Wqh[d * R_ + r];
        k8[j2] = (f16)Wkh[d * R_ + r];
      }
      bq[kc][nt] = q8; bk[kc][nt] = k8;
    }

  // ---- stage v into LDS for transpose ----
#pragma unroll
  for (int it = 0; it < 4; ++it) {
    const int i4 = it * 256 + tid, t = i4 >> 4, dq = (i4 & 15) * 4;
    sv[t * 65 + dq    ] = vld[it].x;
    sv[t * 65 + dq + 1] = vld[it].y;
    sv[t * 65 + dq + 2] = vld[it].z;
    sv[t * 65 + dq + 3] = vld[it].w;
  }

  // ---- projections: D[t-local][r] = A(q) * B(W) ----
  const f32x4 z4 = {0.f, 0.f, 0.f, 0.f};
#pragma unroll
  for (int nt = 0; nt < 2; ++nt) {
    f32x4 accq = mfma16(aq[0], bq[0][nt], z4);
    accq = mfma16(aq[1], bq[1][nt], accq);
    f32x4 acck = mfma16(ak[0], bk[0][nt], z4);
    acck = mfma16(ak[1], bk[1][nt], acck);
    const int r = 16 * nt + l15;
    // kron * (1/sqrt(32)) * log2(e): exp2-domain scores
    const float scl = c1[h * 4 + (r >> 3)] * c2[h * 8 + (r & 7)] *
                      (0.17677669529663687f * 1.4426950408889634f);
#pragma unroll
    for (int i = 0; i < 4; ++i) {   // C/D: row = 4*l4+i, col = l15
      const size_t row = (size_t)bh * T_ + t0 + 16 * w + 4 * l4 + i;
      qlr[row * R_ + r] = (f16)(accq[i] * scl);
      klr[row * R_ + r] = (f16)acck[i];
    }
  }

  __syncthreads();
  // ---- transposed, swizzled V^T write ----
#pragma unroll
  for (int it = 0; it < 8; ++it) {
    const int idx = it * 256 + tid, d = idx >> 5, t = (idx & 31) * 2;
    const float f0 = sv[t * 65 + d], f1 = sv[t * 65 + 65 + d];
    f16x2 pr; pr[0] = (f16)f0; pr[1] = (f16)f1;
    const int sw = ((((t >> 3) ^ (d & 7)) << 3) | (t & 7));
    *(f16x2*)(vt + ((size_t)bh * D_ + d) * T_ + t0 + sw) = pr;
  }
}

// ---------------- Kernel B: flash attention, S^T formulation ----------------
// Block = 64 q-rows (2 waves x 32 m). Per 64-col n-chunk:
//   S^T = Klr @ Qlr^T  (C rows = n, cols = m -> softmax state is scalar/lane)
//   P packed as f16x4 b64 writes into swizzled s_p[m][n]
//   O^T += V^T @ P^T via mfma_32x32x16 (halves V LDS re-reads per MAC)
__global__ __launch_bounds__(128) void attn_kernel(
    const f16* __restrict__ qlr, const f16* __restrict__ klr,
    const f16* __restrict__ vt, float* __restrict__ out)
{
  __shared__ __align__(16) f16 s_k[64 * 32];       // 4 KB  [n][r] flat (DMA dest)
  __shared__ __align__(16) f16 s_vt[64 * 64];      // 8 KB  [d][n] swizzled (DMA dest)
  __shared__ __align__(16) f16 s_p[2][32 * 64];    // 8 KB  per-wave P^T, swizzled

  const int tid = threadIdx.x, w = tid >> 6, lane = tid & 63;
  const int l15 = lane & 15, l4 = lane >> 4, l31 = lane & 31, hh = lane >> 5;
  const int bh = blockIdx.x & 31;
  const int mt = 31 - (blockIdx.x >> 5);     // longest rows dispatch first
  const int m0 = mt * 64;

  // persistent Q B-frags: B[k=r][col=m-local], wave w owns m in [m0+32w, m0+32w+32)
  const f16x8 aq0 = *(const f16x8*)(qlr + ((size_t)bh * T_ + m0 + 32 * w + l15) * R_ + 8 * l4);
  const f16x8 aq1 = *(const f16x8*)(qlr + ((size_t)bh * T_ + m0 + 32 * w + 16 + l15) * R_ + 8 * l4);

  const f16* kb = klr + (size_t)bh * T_ * R_;
  const f16* vb = vt + (size_t)bh * D_ * T_;

  f32x16 oacc[2];
#pragma unroll
  for (int c = 0; c < 2; ++c)
#pragma unroll
    for (int e = 0; e < 16; ++e) oacc[c][e] = 0.f;
  float mi0 = -1e30f, mi1 = -1e30f, li0 = 0.f, li1 = 0.f;
  const f32x4 z4 = {0.f, 0.f, 0.f, 0.f};

  for (int j = 0; j <= mt; ++j) {
    const int n0 = 64 * j;
    __syncthreads();   // prior chunk's LDS reads done
    // ---- async stage: klr 4 KB (2 issues/wave), vt 8 KB (4 issues/wave) ----
#pragma unroll
    for (int e = 0; e < 2; ++e)
      ld_lds16((const char*)kb + (size_t)n0 * 64 + (2 * w + e) * 1024 + lane * 16,
               (char*)s_k + (2 * w + e) * 1024);
#pragma unroll
    for (int e = 0; e < 4; ++e) {
      const int d0 = w * 32 + e * 8;
      ld_lds16((const char*)vb + ((size_t)(d0 + (lane >> 3)) * T_ + n0) * 2 + (lane & 7) * 16,
               (char*)s_vt + d0 * 128);
    }
    __syncthreads();

    // ---- S^T: D[n-local][m-local], A = Klr frag, B = Q frag ----
    f32x4 sc[4][2];
#pragma unroll
    for (int ns = 0; ns < 4; ++ns) {
      f16x8 akf = *(const f16x8*)&s_k[(16 * ns + l15) * 32 + 8 * l4];
      sc[ns][0] = mfma16(akf, aq0, z4);
      sc[ns][1] = mfma16(akf, aq1, z4);
    }
    // causal mask: only final chunk (n0 == m0) straddles the diagonal
    if (j == mt) {
      const int lim0 = 32 * w + l15;          // m_g - n0 for m-sub 0
#pragma unroll
      for (int ns = 0; ns < 4; ++ns) {
        const int nb = 16 * ns + 4 * l4;
#pragma unroll
        for (int i = 0; i < 4; ++i) {
          if (nb + i > lim0)      sc[ns][0][i] = -1e30f;
          if (nb + i > lim0 + 16) sc[ns][1][i] = -1e30f;
        }
      }
    }

    // ---- online softmax (exp2 domain; scalar state per lane per m-sub) ----
    float rm0 = -1e30f, rm1 = -1e30f;
#pragma unroll
    for (int ns = 0; ns < 4; ++ns)
#pragma unroll
      for (int i = 0; i < 4; ++i) {
        rm0 = fmaxf(rm0, sc[ns][0][i]);
        rm1 = fmaxf(rm1, sc[ns][1][i]);
      }
    rm0 = fmaxf(rm0, __shfl_xor(rm0, 16)); rm0 = fmaxf(rm0, __shfl_xor(rm0, 32));
    rm1 = fmaxf(rm1, __shfl_xor(rm1, 16)); rm1 = fmaxf(rm1, __shfl_xor(rm1, 32));
    const float mn0 = fmaxf(mi0, rm0), mn1 = fmaxf(mi1, rm1);
    const float a0 = exp2f(mi0 - mn0), a1 = exp2f(mi1 - mn1);
    float rs0 = 0.f, rs1 = 0.f;
#pragma unroll
    for (int ns = 0; ns < 4; ++ns) {
      f16x4 p0v, p1v;
#pragma unroll
      for (int i = 0; i < 4; ++i) {
        const float p0 = exp2f(sc[ns][0][i] - mn0);
        const float p1 = exp2f(sc[ns][1][i] - mn1);
        rs0 += p0; rs1 += p1;
        p0v[i] = (f16)p0; p1v[i] = (f16)p1;
      }
      // s_p[m][n] swizzled: unit u = n>>3 stored at u^(m&7); n = 16ns+4l4+i
      const int col = ((((2 * ns + (l4 >> 1)) ^ (l15 & 7)) << 3) | (4 * (l4 & 1)));
      *(f16x4*)&s_p[w][l15 * 64 + col]        = p0v;
      *(f16x4*)&s_p[w][(16 + l15) * 64 + col] = p1v;
    }
    rs0 += __shfl_xor(rs0, 16); rs0 += __shfl_xor(rs0, 32);
    rs1 += __shfl_xor(rs1, 16); rs1 += __shfl_xor(rs1, 32);
    li0 = li0 * a0 + rs0; li1 = li1 * a1 + rs1;
    mi0 = mn0; mi1 = mn1;
    const float aPV = (lane & 16) ? a1 : a0;   // PV col m = l31; l31&16 selects m-sub
#pragma unroll
    for (int c = 0; c < 2; ++c) oacc[c] *= aPV;

    // ---- O^T += V^T @ P^T  (mfma_32x32x16: A[d][n], B[n][m]) ----
#pragma unroll
    for (int kc = 0; kc < 4; ++kc) {
      const int u = (2 * kc + hh) ^ (l31 & 7);   // same swizzle for s_p and s_vt rows
      f16x8 bp = *(const f16x8*)&s_p[w][l31 * 64 + u * 8];
#pragma unroll
      for (int c = 0; c < 2; ++c) {
        f16x8 av = *(const f16x8*)&s_vt[(32 * c + l31) * 64 + u * 8];
        oacc[c] = mfma32(av, bp, oacc[c]);
      }
    }
  }

  // ---- epilogue: normalize, float4 stores (C: col=l31=m, row=(e)+8g+4hh=d-local) ----
  const float invl = 1.f / ((lane & 16) ? li1 : li0);
  float* ob = out + ((size_t)bh * T_ + m0 + 32 * w + l31) * D_;
#pragma unroll
  for (int c = 0; c < 2; ++c)
#pragma unroll
    for (int g = 0; g < 4; ++g) {
      f32x4 o;
#pragma unroll
      for (int e = 0; e < 4; ++e) o[e] = oacc[c][4 * g + e] * invl;
      *(f32x4*)(ob + 32 * c + 8 * g + 4 * hh) = o;
    }
}

extern "C" void kernel_launch(void* const* d_in, const int* in_sizes, int n_in,
                              void* d_out, int out_size, void* d_ws, size_t ws_size,
                              hipStream_t stream) {
  const float* q  = (const float*)d_in[0];
  const float* k  = (const float*)d_in[1];
  const float* v  = (const float*)d_in[2];
  const float* Wq = (const float*)d_in[3];
  const float* Wk = (const float*)d_in[4];
  const float* c1 = (const float*)d_in[5];
  const float* c2 = (const float*)d_in[6];
  float* out = (float*)d_out;

  f16* qlr = (f16*)d_ws;                          // 4 MiB
  f16* klr = qlr + (size_t)B_ * H_ * T_ * R_;     // 4 MiB
  f16* vt  = klr + (size_t)B_ * H_ * T_ * R_;     // 8 MiB

  proj_kernel<<<B_ * H_ * NT, 256, 0, stream>>>(q, k, v, Wq, Wk, c1, c2, qlr, klr, vt);
  attn_kernel<<<B_ * H_ * NT, 128, 0, stream>>>(qlr, klr, vt, out);
}

// Round 3
// 153.729 us; speedup vs baseline: 1.1344x; 1.0539x over previous
//
#include <hip/hip_runtime.h>

typedef _Float16 f16;
typedef _Float16 f16x2 __attribute__((ext_vector_type(2)));
typedef _Float16 f16x4 __attribute__((ext_vector_type(4)));
typedef _Float16 f16x8 __attribute__((ext_vector_type(8)));
typedef float    f32x4 __attribute__((ext_vector_type(4)));
typedef float    f32x16 __attribute__((ext_vector_type(16)));

constexpr int B_ = 2, H_ = 16, T_ = 2048, D_ = 64, R_ = 32, NT = 32;
constexpr int NROW = B_ * H_ * T_;   // 65536 (bh,t) rows

__device__ __forceinline__ f32x4 mfma16(f16x8 a, f16x8 b, f32x4 c) {
  return __builtin_amdgcn_mfma_f32_16x16x32_f16(a, b, c, 0, 0, 0);
}
__device__ __forceinline__ f32x16 mfma32(f16x8 a, f16x8 b, f32x16 c) {
  return __builtin_amdgcn_mfma_f32_32x32x16_f16(a, b, c, 0, 0, 0);
}
__device__ __forceinline__ void ld_lds16(const void* g, void* l) {
  __builtin_amdgcn_global_load_lds(
      (const __attribute__((address_space(1))) unsigned int*)g,
      (__attribute__((address_space(3))) unsigned int*)l, 16, 0, 0);
}

// ---------------- Kernel A: MFMA projections + swizzled V^T (unchanged r2) ----------------
__global__ __launch_bounds__(256) void proj_kernel(
    const float* __restrict__ q, const float* __restrict__ k, const float* __restrict__ v,
    const float* __restrict__ Wq, const float* __restrict__ Wk,
    const float* __restrict__ c1, const float* __restrict__ c2,
    f16* __restrict__ qlr, f16* __restrict__ klr, f16* __restrict__ vt)
{
  __shared__ float sv[64 * 65];

  const int tid = threadIdx.x, w = tid >> 6, lane = tid & 63;
  const int l15 = lane & 15, l4 = lane >> 4;
  const int bh = blockIdx.x >> 5, h = bh & (H_ - 1);
  const int t0 = (blockIdx.x & 31) * 64;

  const float* vb = v + ((size_t)bh * T_ + t0) * D_;
  float4 vld[4];
#pragma unroll
  for (int it = 0; it < 4; ++it) vld[it] = ((const float4*)vb)[it * 256 + tid];

  const int m = t0 + 16 * w + l15;
  const float* qr = q + ((size_t)bh * T_ + m) * D_;
  const float* kr = k + ((size_t)bh * T_ + m) * D_;
  f16x8 aq[2], ak[2];
#pragma unroll
  for (int kc = 0; kc < 2; ++kc) {
    float4 x0 = *(const float4*)(qr + kc * 32 + 8 * l4);
    float4 x1 = *(const float4*)(qr + kc * 32 + 8 * l4 + 4);
    float4 y0 = *(const float4*)(kr + kc * 32 + 8 * l4);
    float4 y1 = *(const float4*)(kr + kc * 32 + 8 * l4 + 4);
    f16x8 A, K;
    A[0]=(f16)x0.x; A[1]=(f16)x0.y; A[2]=(f16)x0.z; A[3]=(f16)x0.w;
    A[4]=(f16)x1.x; A[5]=(f16)x1.y; A[6]=(f16)x1.z; A[7]=(f16)x1.w;
    K[0]=(f16)y0.x; K[1]=(f16)y0.y; K[2]=(f16)y0.z; K[3]=(f16)y0.w;
    K[4]=(f16)y1.x; K[5]=(f16)y1.y; K[6]=(f16)y1.z; K[7]=(f16)y1.w;
    aq[kc] = A; ak[kc] = K;
  }

  const float* Wqh = Wq + (size_t)h * D_ * R_;
  const float* Wkh = Wk + (size_t)h * D_ * R_;
  f16x8 bq[2][2], bk[2][2];
#pragma unroll
  for (int kc = 0; kc < 2; ++kc)
#pragma unroll
    for (int nt = 0; nt < 2; ++nt) {
      const int r = 16 * nt + l15;
      f16x8 q8, k8;
#pragma unroll
      for (int j2 = 0; j2 < 8; ++j2) {
        const int d = kc * 32 + 8 * l4 + j2;
        q8[j2] = (f16)Wqh[d * R_ + r];
        k8[j2] = (f16)Wkh[d * R_ + r];
      }
      bq[kc][nt] = q8; bk[kc][nt] = k8;
    }

#pragma unroll
  for (int it = 0; it < 4; ++it) {
    const int i4 = it * 256 + tid, t = i4 >> 4, dq = (i4 & 15) * 4;
    sv[t * 65 + dq    ] = vld[it].x;
    sv[t * 65 + dq + 1] = vld[it].y;
    sv[t * 65 + dq + 2] = vld[it].z;
    sv[t * 65 + dq + 3] = vld[it].w;
  }

  const f32x4 z4 = {0.f, 0.f, 0.f, 0.f};
#pragma unroll
  for (int nt = 0; nt < 2; ++nt) {
    f32x4 accq = mfma16(aq[0], bq[0][nt], z4);
    accq = mfma16(aq[1], bq[1][nt], accq);
    f32x4 acck = mfma16(ak[0], bk[0][nt], z4);
    acck = mfma16(ak[1], bk[1][nt], acck);
    const int r = 16 * nt + l15;
    const float scl = c1[h * 4 + (r >> 3)] * c2[h * 8 + (r & 7)] *
                      (0.17677669529663687f * 1.4426950408889634f);
#pragma unroll
    for (int i = 0; i < 4; ++i) {
      const size_t row = (size_t)bh * T_ + t0 + 16 * w + 4 * l4 + i;
      qlr[row * R_ + r] = (f16)(accq[i] * scl);
      klr[row * R_ + r] = (f16)acck[i];
    }
  }

  __syncthreads();
#pragma unroll
  for (int it = 0; it < 8; ++it) {
    const int idx = it * 256 + tid, d = idx >> 5, t = (idx & 31) * 2;
    const float f0 = sv[t * 65 + d], f1 = sv[t * 65 + 65 + d];
    f16x2 pr; pr[0] = (f16)f0; pr[1] = (f16)f1;
    const int sw = ((((t >> 3) ^ (d & 7)) << 3) | (t & 7));
    *(f16x2*)(vt + ((size_t)bh * D_ + d) * T_ + t0 + sw) = pr;
  }
}

// ---------------- Kernel B: flash attention, n-split flash-decoding ----------------
// Split s of NS handles n-chunks j ≡ s (mod NS); emits normalized partial O (f16)
// and (m,l) per row. Grid: 32 bh × 32 mt × NS, longest-first.
__global__ __launch_bounds__(128) void attn_kernel(
    const f16* __restrict__ qlr, const f16* __restrict__ klr,
    const f16* __restrict__ vt, f16* __restrict__ On, float2* __restrict__ ml,
    const int NS)
{
  __shared__ __align__(16) f16 s_k[64 * 32];
  __shared__ __align__(16) f16 s_vt[64 * 64];
  __shared__ __align__(16) f16 s_p[2][32 * 64];

  const int tid = threadIdx.x, w = tid >> 6, lane = tid & 63;
  const int l15 = lane & 15, l4 = lane >> 4, l31 = lane & 31, hh = lane >> 5;
  const int bh = blockIdx.x & 31;
  const int rest = blockIdx.x >> 5;
  const int mt = 31 - ((NS == 2) ? (rest >> 1) : rest);
  const int s  = rest & (NS - 1);
  const int m0 = mt * 64;

  const f16x8 aq0 = *(const f16x8*)(qlr + ((size_t)bh * T_ + m0 + 32 * w + l15) * R_ + 8 * l4);
  const f16x8 aq1 = *(const f16x8*)(qlr + ((size_t)bh * T_ + m0 + 32 * w + 16 + l15) * R_ + 8 * l4);

  const f16* kb = klr + (size_t)bh * T_ * R_;
  const f16* vb = vt + (size_t)bh * D_ * T_;

  f32x16 oacc[2];
#pragma unroll
  for (int c = 0; c < 2; ++c)
#pragma unroll
    for (int e = 0; e < 16; ++e) oacc[c][e] = 0.f;
  float mi0 = -1e30f, mi1 = -1e30f, li0 = 0.f, li1 = 0.f;
  const f32x4 z4 = {0.f, 0.f, 0.f, 0.f};

  for (int j = s; j <= mt; j += NS) {
    const int n0 = 64 * j;
    __syncthreads();
#pragma unroll
    for (int e = 0; e < 2; ++e)
      ld_lds16((const char*)kb + (size_t)n0 * 64 + (2 * w + e) * 1024 + lane * 16,
               (char*)s_k + (2 * w + e) * 1024);
#pragma unroll
    for (int e = 0; e < 4; ++e) {
      const int d0 = w * 32 + e * 8;
      ld_lds16((const char*)vb + ((size_t)(d0 + (lane >> 3)) * T_ + n0) * 2 + (lane & 7) * 16,
               (char*)s_vt + d0 * 128);
    }
    __syncthreads();

    f32x4 sc[4][2];
#pragma unroll
    for (int ns = 0; ns < 4; ++ns) {
      f16x8 akf = *(const f16x8*)&s_k[(16 * ns + l15) * 32 + 8 * l4];
      sc[ns][0] = mfma16(akf, aq0, z4);
      sc[ns][1] = mfma16(akf, aq1, z4);
    }
    if (j == mt) {
      const int lim0 = 32 * w + l15;
#pragma unroll
      for (int ns = 0; ns < 4; ++ns) {
        const int nb = 16 * ns + 4 * l4;
#pragma unroll
        for (int i = 0; i < 4; ++i) {
          if (nb + i > lim0)      sc[ns][0][i] = -1e30f;
          if (nb + i > lim0 + 16) sc[ns][1][i] = -1e30f;
        }
      }
    }

    float rm0 = -1e30f, rm1 = -1e30f;
#pragma unroll
    for (int ns = 0; ns < 4; ++ns)
#pragma unroll
      for (int i = 0; i < 4; ++i) {
        rm0 = fmaxf(rm0, sc[ns][0][i]);
        rm1 = fmaxf(rm1, sc[ns][1][i]);
      }
    rm0 = fmaxf(rm0, __shfl_xor(rm0, 16)); rm0 = fmaxf(rm0, __shfl_xor(rm0, 32));
    rm1 = fmaxf(rm1, __shfl_xor(rm1, 16)); rm1 = fmaxf(rm1, __shfl_xor(rm1, 32));
    const float mn0 = fmaxf(mi0, rm0), mn1 = fmaxf(mi1, rm1);
    const float a0 = exp2f(mi0 - mn0), a1 = exp2f(mi1 - mn1);
    float rs0 = 0.f, rs1 = 0.f;
#pragma unroll
    for (int ns = 0; ns < 4; ++ns) {
      f16x4 p0v, p1v;
#pragma unroll
      for (int i = 0; i < 4; ++i) {
        const float p0 = exp2f(sc[ns][0][i] - mn0);
        const float p1 = exp2f(sc[ns][1][i] - mn1);
        rs0 += p0; rs1 += p1;
        p0v[i] = (f16)p0; p1v[i] = (f16)p1;
      }
      const int col = ((((2 * ns + (l4 >> 1)) ^ (l15 & 7)) << 3) | (4 * (l4 & 1)));
      *(f16x4*)&s_p[w][l15 * 64 + col]        = p0v;
      *(f16x4*)&s_p[w][(16 + l15) * 64 + col] = p1v;
    }
    rs0 += __shfl_xor(rs0, 16); rs0 += __shfl_xor(rs0, 32);
    rs1 += __shfl_xor(rs1, 16); rs1 += __shfl_xor(rs1, 32);
    li0 = li0 * a0 + rs0; li1 = li1 * a1 + rs1;
    mi0 = mn0; mi1 = mn1;
    const float aPV = (lane & 16) ? a1 : a0;
#pragma unroll
    for (int c = 0; c < 2; ++c) oacc[c] *= aPV;

#pragma unroll
    for (int kc = 0; kc < 4; ++kc) {
      const int u = (2 * kc + hh) ^ (l31 & 7);
      f16x8 bp = *(const f16x8*)&s_p[w][l31 * 64 + u * 8];
#pragma unroll
      for (int c = 0; c < 2; ++c) {
        f16x8 av = *(const f16x8*)&s_vt[(32 * c + l31) * 64 + u * 8];
        oacc[c] = mfma32(av, bp, oacc[c]);
      }
    }
  }

  // ---- epilogue: normalized partial O (f16) + (m,l) ----
  const float myl = (lane & 16) ? li1 : li0;
  const float invl = myl > 0.f ? 1.f / myl : 0.f;   // empty split -> zeros, no NaN
  f16* ob = On + (((size_t)s * 32 + bh) * T_ + m0 + 32 * w + l31) * D_;
#pragma unroll
  for (int c = 0; c < 2; ++c)
#pragma unroll
    for (int g = 0; g < 4; ++g) {
      f16x4 o;
#pragma unroll
      for (int e = 0; e < 4; ++e) o[e] = (f16)(oacc[c][4 * g + e] * invl);
      *(f16x4*)(ob + 32 * c + 8 * g + 4 * hh) = o;
    }
  if (l4 < 2) {
    float2 mlv;
    mlv.x = l4 ? mi1 : mi0;
    mlv.y = l4 ? li1 : li0;
    ml[((size_t)s * 32 + bh) * T_ + m0 + 32 * w + 16 * l4 + l15] = mlv;
  }
}

// ---------------- Kernel C: merge n-split partials ----------------
__global__ __launch_bounds__(256) void merge_kernel(
    const f16* __restrict__ On, const float2* __restrict__ ml,
    float* __restrict__ out, const int NS)
{
  const int row = blockIdx.x * 32 + (threadIdx.x >> 3);
  const int d0 = (threadIdx.x & 7) * 8;
  const f16x8 o0 = *(const f16x8*)(On + (size_t)row * 64 + d0);
  float res[8];
  if (NS == 2) {
    const float2 a = ml[row];
    const float2 b = ml[NROW + row];
    const f16x8 o1 = *(const f16x8*)(On + ((size_t)NROW + row) * 64 + d0);
    const float ms = fmaxf(a.x, b.x);
    const float w0 = exp2f(a.x - ms) * a.y;
    const float w1 = exp2f(b.x - ms) * b.y;
    const float inv = 1.f / (w0 + w1);
    const float c0 = w0 * inv, c1 = w1 * inv;
#pragma unroll
    for (int e = 0; e < 8; ++e) res[e] = c0 * (float)o0[e] + c1 * (float)o1[e];
  } else {
#pragma unroll
    for (int e = 0; e < 8; ++e) res[e] = (float)o0[e];
  }
  float* ob = out + (size_t)row * 64 + d0;
  f32x4 r0, r1;
#pragma unroll
  for (int e = 0; e < 4; ++e) { r0[e] = res[e]; r1[e] = res[4 + e]; }
  *(f32x4*)ob = r0;
  *(f32x4*)(ob + 4) = r1;
}

extern "C" void kernel_launch(void* const* d_in, const int* in_sizes, int n_in,
                              void* d_out, int out_size, void* d_ws, size_t ws_size,
                              hipStream_t stream) {
  const float* q  = (const float*)d_in[0];
  const float* k  = (const float*)d_in[1];
  const float* v  = (const float*)d_in[2];
  const float* Wq = (const float*)d_in[3];
  const float* Wk = (const float*)d_in[4];
  const float* c1 = (const float*)d_in[5];
  const float* c2 = (const float*)d_in[6];
  float* out = (float*)d_out;

  f16* qlr = (f16*)d_ws;                                   // 4 MiB
  f16* klr = qlr + (size_t)B_ * H_ * T_ * R_;              // 4 MiB
  f16* vt  = klr + (size_t)B_ * H_ * T_ * R_;              // 8 MiB
  f16* On  = vt + (size_t)B_ * H_ * T_ * D_;               // up to 16 MiB (NS=2)
  float2* ml = (float2*)(On + (size_t)2 * NROW * D_);      // 1 MiB

  // bytes needed for NS=2: 16M (proj) + 16M (On) + 1M (ml)
  const int NS = (ws_size >= ((size_t)33 * 1024 * 1024 + (1 << 20))) ? 2 : 1;

  proj_kernel<<<B_ * H_ * NT, 256, 0, stream>>>(q, k, v, Wq, Wk, c1, c2, qlr, klr, vt);
  attn_kernel<<<B_ * H_ * NT * NS, 128, 0, stream>>>(qlr, klr, vt, On, ml, NS);
  merge_kernel<<<NROW / 32, 256, 0, stream>>>(On, ml, out, NS);
}